// Round 8
// baseline (475.724 us; speedup 1.0000x reference)
//
#include <hip/hip_runtime.h>

// SigMMDLoss, fully flattened (derivation in earlier rounds):
//   per-row: A = p[4095]-p[0]; S3 = p[4095] - SP_row/n; S4 = (A^2+S6)/2;
//            S6 = sum d^2; S8 = sum d^3;  time-only features cancel.
// Global sums (signed real - gen): SPall, D2, D3 (stream),
//   G1 = sum_rows A, G2 = sum_rows A^2, G3 = sum_rows p[4095] (edges).
// Finalize: SP_excl = SPall - G3;
//   FA=G1/B; FS3=(G3 - SP_excl/n)/B; FS4=.5(G2+D2)/B; FS6=D2/B; FS8=D3/B
//   out = sum F^2.
//
// Round-8: single fused dispatch. Stream structure identical to r7 (nt
// float4 loads, lane-shuffle seams, 8 chunks/thread). Edge rows folded in
// (2 per block). Finalize done by the LAST block to finish (atomic counter,
// release/acquire threadfence, agent-scope atomic partial stores/loads to
// dodge cross-XCD stale-L2 on the 0xAA-poisoned ws). Counter zeroed by a
// 4-byte hipMemsetAsync before the kernel (graph-capture legal).

typedef float vfloat4 __attribute__((ext_vector_type(4)));

constexpr int T_LEN = 4096;
constexpr int B_ROWS = 4096;
constexpr int F4_PER_ARRAY = B_ROWS * T_LEN / 4;      // 4,194,304
constexpr int CHUNKS = 8;                             // float4s per thread
constexpr int STRIPES = CHUNKS / 2;                   // 4 stripes per array
constexpr int THREADS_TOTAL = F4_PER_ARRAY / STRIPES; // 1,048,576
constexpr int NBLK = THREADS_TOTAL / 256;             // 4096
constexpr int NQ = 6;                                 // sp,d2,d3,g1,g2,g3

__global__ __launch_bounds__(256) void sig_all(const float* __restrict__ real,
                                               const float* __restrict__ gen,
                                               double* __restrict__ P,
                                               unsigned int* __restrict__ counter,
                                               float* __restrict__ out) {
  const int tid = threadIdx.x;
  const int tid0 = blockIdx.x * 256 + tid;
  const int lane = tid & 63;
  const int wid = tid >> 6;

  __shared__ double sred[4][3];
  __shared__ double eshr[2][3];
  __shared__ int is_last;

  // ---- edge rows: 2 per block (items 2b, 2b+1), threads 0/1 ----
  if (tid < 2) {
    const int e = 2 * blockIdx.x + tid;              // 0..8191
    const int which = e >> 12;
    const int row = e & (B_ROWS - 1);
    const float* p = (which ? gen : real) + (size_t)row * T_LEN;
    const double pf = (double)p[0];
    const double pl = (double)p[T_LEN - 1];
    const double sg = which ? -1.0 : 1.0;
    const double A = pl - pf;
    eshr[tid][0] = sg * A;
    eshr[tid][1] = sg * A * A;
    eshr[tid][2] = sg * pl;
  }

  // ---- stream: 8 nt float4 chunks per thread (r7 structure) ----
  vfloat4 a[CHUNKS];
  float s[CHUNKS];
  int col4[CHUNKS];
#pragma unroll
  for (int i = 0; i < CHUNKS; ++i) {
    const float* base = (i < STRIPES) ? real : gen;
    const int f = tid0 + (i & (STRIPES - 1)) * THREADS_TOTAL;
    col4[i] = f & (T_LEN / 4 - 1);                    // 0..1023
    a[i] = __builtin_nontemporal_load(
        reinterpret_cast<const vfloat4*>(base) + f);
    s[i] = 0.f;
    if (lane == 63 && col4[i] < 1023)
      s[i] = __builtin_nontemporal_load(base + 4 * f + 4);
  }

  float asp = 0.f, as2 = 0.f, as3 = 0.f;
#pragma unroll
  for (int i = 0; i < CHUNKS; ++i) {
    const float sg = (i < STRIPES) ? 1.f : -1.f;
    const float nx = __shfl_down(a[i].x, 1, 64);
    const float nxt = (lane == 63) ? s[i] : nx;
    const float d1 = a[i].y - a[i].x;
    const float d2 = a[i].z - a[i].y;
    const float d3 = a[i].w - a[i].z;
    const float d0 = (col4[i] < 1023) ? (nxt - a[i].w) : 0.f;  // seam diff
    const float e0 = d0 * d0, e1 = d1 * d1, e2 = d2 * d2, e3 = d3 * d3;
    asp += sg * ((a[i].x + a[i].y) + (a[i].z + a[i].w));
    as2 += sg * ((e0 + e1) + (e2 + e3));
    as3 += sg * ((e0 * d0 + e1 * d1) + (e2 * d2 + e3 * d3));
  }

#pragma unroll
  for (int off = 32; off; off >>= 1) {
    asp += __shfl_down(asp, off, 64);
    as2 += __shfl_down(as2, off, 64);
    as3 += __shfl_down(as3, off, 64);
  }
  if (lane == 0) {
    sred[wid][0] = (double)asp;
    sred[wid][1] = (double)as2;
    sred[wid][2] = (double)as3;
  }
  __syncthreads();

  // ---- publish 6 per-block partials (agent-scope atomic stores) ----
  if (tid < NQ) {
    double v;
    if (tid < 3)
      v = sred[0][tid] + sred[1][tid] + sred[2][tid] + sred[3][tid];
    else
      v = eshr[0][tid - 3] + eshr[1][tid - 3];
    __hip_atomic_store(&P[tid * NBLK + blockIdx.x], v, __ATOMIC_RELAXED,
                       __HIP_MEMORY_SCOPE_AGENT);
  }

  // ---- last-block finalize ----
  __threadfence();  // release: partials visible before counter bump
  __syncthreads();
  if (tid == 0) {
    const unsigned int old = atomicAdd(counter, 1u);
    is_last = (old == (unsigned int)(NBLK - 1)) ? 1 : 0;
  }
  __syncthreads();
  if (!is_last) return;
  __threadfence();  // acquire

  double loc[NQ] = {0, 0, 0, 0, 0, 0};
  for (int b = tid; b < NBLK; b += 256)
#pragma unroll
    for (int q = 0; q < NQ; ++q)
      loc[q] += __hip_atomic_load(&P[q * NBLK + b], __ATOMIC_RELAXED,
                                  __HIP_MEMORY_SCOPE_AGENT);
#pragma unroll
  for (int q = 0; q < NQ; ++q)
#pragma unroll
    for (int off = 32; off; off >>= 1) loc[q] += __shfl_down(loc[q], off, 64);

  __shared__ double fred[4][NQ];
  if (lane == 0)
#pragma unroll
    for (int q = 0; q < NQ; ++q) fred[wid][q] = loc[q];
  __syncthreads();
  if (tid == 0) {
    double Q[NQ];
#pragma unroll
    for (int q = 0; q < NQ; ++q)
      Q[q] = fred[0][q] + fred[1][q] + fred[2][q] + fred[3][q];
    const double SPall = Q[0], D2 = Q[1], D3 = Q[2];
    const double G1 = Q[3], G2 = Q[4], G3 = Q[5];
    const double n = (double)(T_LEN - 1), Bn = (double)B_ROWS;
    const double SPex = SPall - G3;
    const double FA = G1 / Bn;
    const double FS3 = (G3 - SPex / n) / Bn;
    const double FS4 = 0.5 * (G2 + D2) / Bn;
    const double FS6 = D2 / Bn;
    const double FS8 = D3 / Bn;
    out[0] = (float)(FA * FA + FS3 * FS3 + FS4 * FS4 + FS6 * FS6 + FS8 * FS8);
  }
}

extern "C" void kernel_launch(void* const* d_in, const int* in_sizes, int n_in,
                              void* d_out, int out_size, void* d_ws, size_t ws_size,
                              hipStream_t stream) {
  const float* real = (const float*)d_in[0];
  const float* gen = (const float*)d_in[1];
  double* P = (double*)d_ws;                          // 6*4096*8 = 192 KB
  unsigned int* counter =
      (unsigned int*)((char*)d_ws + (size_t)NQ * NBLK * sizeof(double));
  float* out = (float*)d_out;

  hipMemsetAsync(counter, 0, sizeof(unsigned int), stream);
  sig_all<<<NBLK, 256, 0, stream>>>(real, gen, P, counter, out);
}